// Round 1
// baseline (462.640 us; speedup 1.0000x reference)
//
#include <hip/hip_runtime.h>

// QuantizeEMAReset forward (eval): VQ quantize + commit loss + perplexity/usage.
// z: [16,4096,64] fp32 -> N=65536 tokens, C=64. codebook: [1024,64] fp32.
// out: [z_q_bar (4194304 f32), commit_loss, ppl, usage] flat.
//
// ws layout (floats): [0,1024): cnorm  [1024,2048): counts  [2048,2304): loss partials

#define NTOK   65536
#define KCODE  1024
#define OUT_SCALARS 4194304

__global__ void prep_kernel(const float* __restrict__ cb, float* __restrict__ ws) {
    int k = blockIdx.x * blockDim.x + threadIdx.x;   // 0..1023
    const float4* cb4 = (const float4*)cb;
    float s = 0.f;
#pragma unroll
    for (int j = 0; j < 16; ++j) {
        float4 v = cb4[k * 16 + j];
        s = fmaf(v.x, v.x, s);
        s = fmaf(v.y, v.y, s);
        s = fmaf(v.z, v.z, s);
        s = fmaf(v.w, v.w, s);
    }
    ws[k] = s;            // cnorm
    ws[1024 + k] = 0.f;   // zero histogram (d_ws is poisoned, never re-poisoned)
}

__launch_bounds__(256, 1)
__global__ void quant_kernel(const float* __restrict__ z,
                             const float* __restrict__ cb,
                             float* __restrict__ out,
                             float* __restrict__ ws) {
    const int tok = blockIdx.x * 256 + threadIdx.x;

    // x into registers (16 x float4; per-lane stride 256B, lines fully reused via L1)
    const float4* z4 = (const float4*)z + tok * 16;
    float4 x[16];
#pragma unroll
    for (int j = 0; j < 16; ++j) x[j] = z4[j];

    const float4* cb4 = (const float4*)cb;
    const float* cnorm = ws;

    float best = 3.4e38f;
    int bidx = 0;

    for (int k0 = 0; k0 < KCODE; k0 += 8) {
        float s[8];
#pragma unroll
        for (int kk = 0; kk < 8; ++kk) s[kk] = 0.f;
#pragma unroll
        for (int j = 0; j < 16; ++j) {
            float4 xv = x[j];
#pragma unroll
            for (int kk = 0; kk < 8; ++kk) {
                float4 cv = cb4[(k0 + kk) * 16 + j];   // wave-uniform -> s_load_dwordx4
                s[kk] = fmaf(xv.x, cv.x, s[kk]);
                s[kk] = fmaf(xv.y, cv.y, s[kk]);
                s[kk] = fmaf(xv.z, cv.z, s[kk]);
                s[kk] = fmaf(xv.w, cv.w, s[kk]);
            }
        }
#pragma unroll
        for (int kk = 0; kk < 8; ++kk) {
            // d = ||c||^2 - 2 x.c   (||x||^2 const per token, dropped for argmin)
            float d = fmaf(-2.f, s[kk], cnorm[k0 + kk]);
            if (d < best) { best = d; bidx = k0 + kk; }   // strict <: first-min like jnp.argmin
        }
    }

    // gather winner, write z_q_bar = x + (z_q - x), accumulate commit loss
    const float4* cq = cb4 + bidx * 16;
    float4* o4 = (float4*)out + tok * 16;
    float ssum = 0.f;
#pragma unroll
    for (int j = 0; j < 16; ++j) {
        float4 xv = x[j];
        float4 qv = cq[j];
        float4 ov;
        float dx;
        dx = qv.x - xv.x; ov.x = xv.x + dx; ssum = fmaf(dx, dx, ssum);
        dx = qv.y - xv.y; ov.y = xv.y + dx; ssum = fmaf(dx, dx, ssum);
        dx = qv.z - xv.z; ov.z = xv.z + dx; ssum = fmaf(dx, dx, ssum);
        dx = qv.w - xv.w; ov.w = xv.w + dx; ssum = fmaf(dx, dx, ssum);
        o4[j] = ov;
    }
    atomicAdd(&ws[1024 + bidx], 1.0f);   // integer-valued float adds: exact, order-independent

    // block-deterministic commit-loss partial: per_tok = ssum/64
    float v = ssum * (1.f / 64.f);
#pragma unroll
    for (int off = 32; off > 0; off >>= 1) v += __shfl_down(v, off, 64);
    __shared__ float wsum[4];
    int lane = threadIdx.x & 63, wid = threadIdx.x >> 6;
    if (lane == 0) wsum[wid] = v;
    __syncthreads();
    if (threadIdx.x == 0)
        ws[2048 + blockIdx.x] = wsum[0] + wsum[1] + wsum[2] + wsum[3];
}

__global__ void final_kernel(const float* __restrict__ ws, float* __restrict__ out) {
    __shared__ float red[1024];
    const int t = threadIdx.x;
    const float c = ws[1024 + t];

    // total = sum(counts)
    red[t] = c; __syncthreads();
    for (int s = 512; s > 0; s >>= 1) { if (t < s) red[t] += red[t + s]; __syncthreads(); }
    const float total = fmaxf(red[0], 1e-6f);
    __syncthreads();

    // entropy sum
    const float p = c / total;
    red[t] = p * logf(p + 1e-7f); __syncthreads();
    for (int s = 512; s > 0; s >>= 1) { if (t < s) red[t] += red[t + s]; __syncthreads(); }
    const float ent = red[0];
    __syncthreads();

    // usage
    red[t] = (c >= 1.f) ? 1.f : 0.f; __syncthreads();
    for (int s = 512; s > 0; s >>= 1) { if (t < s) red[t] += red[t + s]; __syncthreads(); }
    const float used = red[0];
    __syncthreads();

    // commit loss from 256 block partials
    red[t] = (t < 256) ? ws[2048 + t] : 0.f; __syncthreads();
    for (int s = 512; s > 0; s >>= 1) { if (t < s) red[t] += red[t + s]; __syncthreads(); }

    if (t == 0) {
        out[OUT_SCALARS + 0] = red[0] * (1.f / (float)NTOK);
        out[OUT_SCALARS + 1] = expf(-ent);
        out[OUT_SCALARS + 2] = used * (1.f / (float)KCODE);
    }
}

extern "C" void kernel_launch(void* const* d_in, const int* in_sizes, int n_in,
                              void* d_out, int out_size, void* d_ws, size_t ws_size,
                              hipStream_t stream) {
    const float* z  = (const float*)d_in[0];
    const float* cb = (const float*)d_in[1];
    float* out = (float*)d_out;
    float* ws  = (float*)d_ws;   // needs 2304 floats = 9.2 KB

    prep_kernel <<<4, 256, 0, stream>>>(cb, ws);
    quant_kernel<<<NTOK / 256, 256, 0, stream>>>(z, cb, out, ws);
    final_kernel<<<1, 1024, 0, stream>>>(ws, out);
}

// Round 2
// 251.727 us; speedup vs baseline: 1.8379x; 1.8379x over previous
//
#include <hip/hip_runtime.h>

// QuantizeEMAReset forward (eval): VQ quantize + commit loss + perplexity/usage.
// z: [16,4096,64] fp32 -> N=65536 tokens, C=64. codebook: [1024,64] fp32.
// out: [z_q_bar (4194304 f32), commit_loss, ppl, usage] flat.
//
// R2: codebook split 4-ways across blocks -> 1024 blocks (16 waves/CU) to hide
// scalar-load latency (R1: 1 wave/SIMD, VALUBusy 20%). Partial argmins merged
// deterministically via atomicMin on (orderkey(d)<<32 | idx).
//
// ws layout: [0,1024) cnorm | [1024,2048) counts | [2048,2304) loss partials
//            byte 10240+: best[65536] u64   (total ~534 KB)

#define NTOK   65536
#define KCODE  1024
#define NSPLIT 4
#define KPB    (KCODE / NSPLIT)   // 256 codewords per block
#define OUT_SCALARS 4194304

static __device__ __forceinline__ unsigned int order_key(float f) {
    unsigned int u = __float_as_uint(f);
    unsigned int mask = (u >> 31) ? 0xFFFFFFFFu : 0x80000000u;
    return u ^ mask;   // monotone: a<b (float) <=> key(a)<key(b) (uint)
}

__global__ void prep_kernel(const float* __restrict__ cb, float* __restrict__ ws) {
    int t = blockIdx.x * 256 + threadIdx.x;   // 0..65535
    unsigned long long* best = (unsigned long long*)((char*)ws + 10240);
    best[t] = 0xFFFFFFFFFFFFFFFFull;
    if (t < KCODE) {
        const float4* cb4 = (const float4*)cb;
        float s = 0.f;
#pragma unroll
        for (int j = 0; j < 16; ++j) {
            float4 v = cb4[t * 16 + j];
            s = fmaf(v.x, v.x, s);
            s = fmaf(v.y, v.y, s);
            s = fmaf(v.z, v.z, s);
            s = fmaf(v.w, v.w, s);
        }
        ws[t] = s;            // cnorm
        ws[1024 + t] = 0.f;   // zero histogram
    }
}

__launch_bounds__(256, 4)
__global__ void quant_kernel(const float* __restrict__ z,
                             const float* __restrict__ cb,
                             float* __restrict__ ws) {
    const int grp   = blockIdx.x & 255;        // token group
    const int split = blockIdx.x >> 8;         // 0..3
    const int tok   = grp * 256 + threadIdx.x;
    const int kbase = split * KPB;

    const float4* z4 = (const float4*)z + tok * 16;
    float4 x[16];
#pragma unroll
    for (int j = 0; j < 16; ++j) x[j] = z4[j];

    const float4* cb4 = (const float4*)cb;
    const float* cnorm = ws;

    float best = 3.4e38f;
    int bidx = kbase;

    for (int k0 = kbase; k0 < kbase + KPB; k0 += 8) {
        float s[8];
#pragma unroll
        for (int kk = 0; kk < 8; ++kk) s[kk] = 0.f;
#pragma unroll
        for (int j = 0; j < 16; ++j) {
            float4 xv = x[j];
#pragma unroll
            for (int kk = 0; kk < 8; ++kk) {
                float4 cv = cb4[(k0 + kk) * 16 + j];   // wave-uniform -> s_load
                s[kk] = fmaf(xv.x, cv.x, s[kk]);
                s[kk] = fmaf(xv.y, cv.y, s[kk]);
                s[kk] = fmaf(xv.z, cv.z, s[kk]);
                s[kk] = fmaf(xv.w, cv.w, s[kk]);
            }
        }
#pragma unroll
        for (int kk = 0; kk < 8; ++kk) {
            // d = ||c||^2 - 2 x.c  (||x||^2 const per token, dropped for argmin)
            float d = fmaf(-2.f, s[kk], cnorm[k0 + kk]);
            if (d < best) { best = d; bidx = k0 + kk; }   // strict <: first-min
        }
    }

    // merge partial argmin: min over (key(d), idx) pairs == global first-min
    unsigned long long* bestq = (unsigned long long*)((char*)ws + 10240);
    unsigned long long pk = ((unsigned long long)order_key(best) << 32) |
                            (unsigned long long)(unsigned int)bidx;
    atomicMin(&bestq[tok], pk);
}

__global__ void gather_kernel(const float* __restrict__ z,
                              const float* __restrict__ cb,
                              float* __restrict__ out,
                              float* __restrict__ ws) {
    const int tok = blockIdx.x * 256 + threadIdx.x;
    const unsigned long long* bestq =
        (const unsigned long long*)((const char*)ws + 10240);
    const int idx = (int)(unsigned int)bestq[tok];

    atomicAdd(&ws[1024 + idx], 1.0f);   // integer-valued adds: exact, order-indep

    const float4* z4 = (const float4*)z + tok * 16;
    const float4* cq = (const float4*)cb + idx * 16;
    float4* o4 = (float4*)out + tok * 16;
    float ssum = 0.f;
#pragma unroll
    for (int j = 0; j < 16; ++j) {
        float4 xv = z4[j];
        float4 qv = cq[j];
        float4 ov;
        float dx;
        dx = qv.x - xv.x; ov.x = xv.x + dx; ssum = fmaf(dx, dx, ssum);
        dx = qv.y - xv.y; ov.y = xv.y + dx; ssum = fmaf(dx, dx, ssum);
        dx = qv.z - xv.z; ov.z = xv.z + dx; ssum = fmaf(dx, dx, ssum);
        dx = qv.w - xv.w; ov.w = xv.w + dx; ssum = fmaf(dx, dx, ssum);
        o4[j] = ov;
    }

    // block-deterministic commit-loss partial: per_tok = ssum/64
    float v = ssum * (1.f / 64.f);
#pragma unroll
    for (int off = 32; off > 0; off >>= 1) v += __shfl_down(v, off, 64);
    __shared__ float wsum[4];
    int lane = threadIdx.x & 63, wid = threadIdx.x >> 6;
    if (lane == 0) wsum[wid] = v;
    __syncthreads();
    if (threadIdx.x == 0)
        ws[2048 + blockIdx.x] = wsum[0] + wsum[1] + wsum[2] + wsum[3];
}

__global__ void final_kernel(const float* __restrict__ ws, float* __restrict__ out) {
    __shared__ float red[1024];
    const int t = threadIdx.x;
    const float c = ws[1024 + t];

    red[t] = c; __syncthreads();
    for (int s = 512; s > 0; s >>= 1) { if (t < s) red[t] += red[t + s]; __syncthreads(); }
    const float total = fmaxf(red[0], 1e-6f);
    __syncthreads();

    const float p = c / total;
    red[t] = p * logf(p + 1e-7f); __syncthreads();
    for (int s = 512; s > 0; s >>= 1) { if (t < s) red[t] += red[t + s]; __syncthreads(); }
    const float ent = red[0];
    __syncthreads();

    red[t] = (c >= 1.f) ? 1.f : 0.f; __syncthreads();
    for (int s = 512; s > 0; s >>= 1) { if (t < s) red[t] += red[t + s]; __syncthreads(); }
    const float used = red[0];
    __syncthreads();

    red[t] = (t < 256) ? ws[2048 + t] : 0.f; __syncthreads();
    for (int s = 512; s > 0; s >>= 1) { if (t < s) red[t] += red[t + s]; __syncthreads(); }

    if (t == 0) {
        out[OUT_SCALARS + 0] = red[0] * (1.f / (float)NTOK);
        out[OUT_SCALARS + 1] = expf(-ent);
        out[OUT_SCALARS + 2] = used * (1.f / (float)KCODE);
    }
}

extern "C" void kernel_launch(void* const* d_in, const int* in_sizes, int n_in,
                              void* d_out, int out_size, void* d_ws, size_t ws_size,
                              hipStream_t stream) {
    const float* z  = (const float*)d_in[0];
    const float* cb = (const float*)d_in[1];
    float* out = (float*)d_out;
    float* ws  = (float*)d_ws;   // needs ~534 KB

    prep_kernel  <<<NTOK / 256, 256, 0, stream>>>(cb, ws);
    quant_kernel <<<(NTOK / 256) * NSPLIT, 256, 0, stream>>>(z, cb, ws);
    gather_kernel<<<NTOK / 256, 256, 0, stream>>>(z, cb, out, ws);
    final_kernel <<<1, 1024, 0, stream>>>(ws, out);
}

// Round 3
// 212.808 us; speedup vs baseline: 2.1740x; 1.1829x over previous
//
#include <hip/hip_runtime.h>

// QuantizeEMAReset forward (eval): VQ quantize + commit loss + perplexity/usage.
// z: [16,4096,64] fp32 -> N=65536 tokens, C=64. codebook: [1024,64] fp32.
// out: [z_q_bar (4194304 f32), commit_loss, ppl, usage] flat.
//
// R3: R2 + pin x[16] in VGPRs via empty asm (R2 rocprof: VGPR=36 -> compiler
// rematerialized x from global every k-chunk, capping VALUBusy at 60%).
//
// ws layout: [0,1024) cnorm | [1024,2048) counts | [2048,2304) loss partials
//            byte 10240+: best[65536] u64   (total ~534 KB)

#define NTOK   65536
#define KCODE  1024
#define NSPLIT 4
#define KPB    (KCODE / NSPLIT)   // 256 codewords per block
#define OUT_SCALARS 4194304

static __device__ __forceinline__ unsigned int order_key(float f) {
    unsigned int u = __float_as_uint(f);
    unsigned int mask = (u >> 31) ? 0xFFFFFFFFu : 0x80000000u;
    return u ^ mask;   // monotone: a<b (float) <=> key(a)<key(b) (uint)
}

__global__ void prep_kernel(const float* __restrict__ cb, float* __restrict__ ws) {
    int t = blockIdx.x * 256 + threadIdx.x;   // 0..65535
    unsigned long long* best = (unsigned long long*)((char*)ws + 10240);
    best[t] = 0xFFFFFFFFFFFFFFFFull;
    if (t < KCODE) {
        const float4* cb4 = (const float4*)cb;
        float s = 0.f;
#pragma unroll
        for (int j = 0; j < 16; ++j) {
            float4 v = cb4[t * 16 + j];
            s = fmaf(v.x, v.x, s);
            s = fmaf(v.y, v.y, s);
            s = fmaf(v.z, v.z, s);
            s = fmaf(v.w, v.w, s);
        }
        ws[t] = s;            // cnorm
        ws[1024 + t] = 0.f;   // zero histogram
    }
}

__launch_bounds__(256, 4)
__global__ void quant_kernel(const float* __restrict__ z,
                             const float* __restrict__ cb,
                             float* __restrict__ ws) {
    const int grp   = blockIdx.x & 255;        // token group
    const int split = blockIdx.x >> 8;         // 0..3
    const int tok   = grp * 256 + threadIdx.x;
    const int kbase = split * KPB;

    const float4* z4 = (const float4*)z + tok * 16;
    float4 x[16];
#pragma unroll
    for (int j = 0; j < 16; ++j) x[j] = z4[j];
    // Pin x in VGPRs: redefine through empty asm so the compiler cannot
    // rematerialize from the global load (R2 showed it re-loads every chunk).
#pragma unroll
    for (int j = 0; j < 16; ++j) {
        asm volatile("" : "+v"(x[j].x), "+v"(x[j].y), "+v"(x[j].z), "+v"(x[j].w));
    }

    const float4* cb4 = (const float4*)cb;
    const float* cnorm = ws;

    float best = 3.4e38f;
    int bidx = kbase;

    for (int k0 = kbase; k0 < kbase + KPB; k0 += 8) {
        float s[8];
#pragma unroll
        for (int kk = 0; kk < 8; ++kk) s[kk] = 0.f;
#pragma unroll
        for (int j = 0; j < 16; ++j) {
            float4 xv = x[j];
#pragma unroll
            for (int kk = 0; kk < 8; ++kk) {
                float4 cv = cb4[(k0 + kk) * 16 + j];   // wave-uniform -> s_load
                s[kk] = fmaf(xv.x, cv.x, s[kk]);
                s[kk] = fmaf(xv.y, cv.y, s[kk]);
                s[kk] = fmaf(xv.z, cv.z, s[kk]);
                s[kk] = fmaf(xv.w, cv.w, s[kk]);
            }
        }
#pragma unroll
        for (int kk = 0; kk < 8; ++kk) {
            // d = ||c||^2 - 2 x.c  (||x||^2 const per token, dropped for argmin)
            float d = fmaf(-2.f, s[kk], cnorm[k0 + kk]);
            if (d < best) { best = d; bidx = k0 + kk; }   // strict <: first-min
        }
    }

    // merge partial argmin: min over (key(d), idx) pairs == global first-min
    unsigned long long* bestq = (unsigned long long*)((char*)ws + 10240);
    unsigned long long pk = ((unsigned long long)order_key(best) << 32) |
                            (unsigned long long)(unsigned int)bidx;
    atomicMin(&bestq[tok], pk);
}

__global__ void gather_kernel(const float* __restrict__ z,
                              const float* __restrict__ cb,
                              float* __restrict__ out,
                              float* __restrict__ ws) {
    const int tok = blockIdx.x * 256 + threadIdx.x;
    const unsigned long long* bestq =
        (const unsigned long long*)((const char*)ws + 10240);
    const int idx = (int)(unsigned int)bestq[tok];

    atomicAdd(&ws[1024 + idx], 1.0f);   // integer-valued adds: exact, order-indep

    const float4* z4 = (const float4*)z + tok * 16;
    const float4* cq = (const float4*)cb + idx * 16;
    float4* o4 = (float4*)out + tok * 16;
    float ssum = 0.f;
#pragma unroll
    for (int j = 0; j < 16; ++j) {
        float4 xv = z4[j];
        float4 qv = cq[j];
        float4 ov;
        float dx;
        dx = qv.x - xv.x; ov.x = xv.x + dx; ssum = fmaf(dx, dx, ssum);
        dx = qv.y - xv.y; ov.y = xv.y + dx; ssum = fmaf(dx, dx, ssum);
        dx = qv.z - xv.z; ov.z = xv.z + dx; ssum = fmaf(dx, dx, ssum);
        dx = qv.w - xv.w; ov.w = xv.w + dx; ssum = fmaf(dx, dx, ssum);
        o4[j] = ov;
    }

    // block-deterministic commit-loss partial: per_tok = ssum/64
    float v = ssum * (1.f / 64.f);
#pragma unroll
    for (int off = 32; off > 0; off >>= 1) v += __shfl_down(v, off, 64);
    __shared__ float wsum[4];
    int lane = threadIdx.x & 63, wid = threadIdx.x >> 6;
    if (lane == 0) wsum[wid] = v;
    __syncthreads();
    if (threadIdx.x == 0)
        ws[2048 + blockIdx.x] = wsum[0] + wsum[1] + wsum[2] + wsum[3];
}

__global__ void final_kernel(const float* __restrict__ ws, float* __restrict__ out) {
    __shared__ float red[1024];
    const int t = threadIdx.x;
    const float c = ws[1024 + t];

    red[t] = c; __syncthreads();
    for (int s = 512; s > 0; s >>= 1) { if (t < s) red[t] += red[t + s]; __syncthreads(); }
    const float total = fmaxf(red[0], 1e-6f);
    __syncthreads();

    const float p = c / total;
    red[t] = p * logf(p + 1e-7f); __syncthreads();
    for (int s = 512; s > 0; s >>= 1) { if (t < s) red[t] += red[t + s]; __syncthreads(); }
    const float ent = red[0];
    __syncthreads();

    red[t] = (c >= 1.f) ? 1.f : 0.f; __syncthreads();
    for (int s = 512; s > 0; s >>= 1) { if (t < s) red[t] += red[t + s]; __syncthreads(); }
    const float used = red[0];
    __syncthreads();

    red[t] = (t < 256) ? ws[2048 + t] : 0.f; __syncthreads();
    for (int s = 512; s > 0; s >>= 1) { if (t < s) red[t] += red[t + s]; __syncthreads(); }

    if (t == 0) {
        out[OUT_SCALARS + 0] = red[0] * (1.f / (float)NTOK);
        out[OUT_SCALARS + 1] = expf(-ent);
        out[OUT_SCALARS + 2] = used * (1.f / (float)KCODE);
    }
}

extern "C" void kernel_launch(void* const* d_in, const int* in_sizes, int n_in,
                              void* d_out, int out_size, void* d_ws, size_t ws_size,
                              hipStream_t stream) {
    const float* z  = (const float*)d_in[0];
    const float* cb = (const float*)d_in[1];
    float* out = (float*)d_out;
    float* ws  = (float*)d_ws;   // needs ~534 KB

    prep_kernel  <<<NTOK / 256, 256, 0, stream>>>(cb, ws);
    quant_kernel <<<(NTOK / 256) * NSPLIT, 256, 0, stream>>>(z, cb, ws);
    gather_kernel<<<NTOK / 256, 256, 0, stream>>>(z, cb, out, ws);
    final_kernel <<<1, 1024, 0, stream>>>(ws, out);
}

// Round 4
// 158.743 us; speedup vs baseline: 2.9144x; 1.3406x over previous
//
#include <hip/hip_runtime.h>

// QuantizeEMAReset forward (eval): VQ quantize + commit loss + perplexity/usage.
// z: [16,4096,64] fp32 -> N=65536 tokens, C=64. codebook: [1024,64] fp32.
// out: [z_q_bar (4194304 f32), commit_loss, ppl, usage] flat.
//
// R4: LDS-tiled register-blocked distance GEMM. One block = 64 tokens x all
// 1024 codes (argmin completes in-block; gather fused). 256 thr, 4x4
// micro-tile/thread. x_lds stride 68 (2-way banks, free); cbT transposed
// (b128 reads across codes, 2-way). Distance fma chain bit-identical to R1.
//
// ws floats: [0,1024) cnorm | [1024,2048) counts | [2048,3072) loss partials

#define NTOK   65536
#define KCODE  1024
#define OUT_SCALARS 4194304
#define NBLK   1024          // 64 tokens per block

static __device__ __forceinline__ unsigned int order_key(float f) {
    unsigned int u = __float_as_uint(f);
    unsigned int mask = (u >> 31) ? 0xFFFFFFFFu : 0x80000000u;
    return u ^ mask;   // monotone: a<b (float) <=> key(a)<key(b) (uint)
}

static __device__ __forceinline__ float f4c(float4 v, int d) {
    union { float4 v; float a[4]; } u; u.v = v; return u.a[d];   // d is unroll-constant
}

__global__ void prep_kernel(const float* __restrict__ cb, float* __restrict__ ws) {
    int t = blockIdx.x * 256 + threadIdx.x;   // 0..1023
    const float4* cb4 = (const float4*)cb;
    float s = 0.f;
#pragma unroll
    for (int j = 0; j < 16; ++j) {
        float4 v = cb4[t * 16 + j];
        s = fmaf(v.x, v.x, s);
        s = fmaf(v.y, v.y, s);
        s = fmaf(v.z, v.z, s);
        s = fmaf(v.w, v.w, s);
    }
    ws[t] = s;            // cnorm (same chain as R1 -> bit-identical)
    ws[1024 + t] = 0.f;   // zero histogram
}

__launch_bounds__(256, 4)
__global__ void quant_kernel(const float* __restrict__ z,
                             const float* __restrict__ cb,
                             float* __restrict__ out,
                             float* __restrict__ ws) {
    const int t    = threadIdx.x;
    const int blk  = blockIdx.x;
    const int tok0 = blk * 64;

    __shared__ __align__(16) float x_lds[64 * 68];     // [tok][dim], stride 68
    __shared__ __align__(16) float cbT_raw[64 * 68];   // [dim][code], stride 68; aliased as u64 red[]
    __shared__ int   win[64];
    __shared__ float lsum[64];

    // ---- stage x tile: 64 tokens x 64 dims, coalesced ----
    {
        const int tokr = t >> 2;
        const int fb   = (t & 3) * 4;      // float4 index base
        const float4* zr = (const float4*)(z + (size_t)(tok0 + tokr) * 64);
#pragma unroll
        for (int j = 0; j < 4; ++j) {
            float4 v = zr[fb + j];
            *(float4*)&x_lds[tokr * 68 + (fb + j) * 4] = v;
        }
    }

    const int r = t >> 4;    // token-row group: tokens 4r..4r+3
    const int c = t & 15;    // code-col group: codes 4c..4c+3 (within tile)
    const float* cnorm = ws;

    unsigned long long best[4] = { ~0ull, ~0ull, ~0ull, ~0ull };

    for (int tile = 0; tile < 16; ++tile) {
        const int c0 = tile * 64;
        __syncthreads();   // tile0: x staged; else: prev tile's cbT reads done
        // ---- stage cbT transposed: read [code][dim] coalesced, write [dim][code] ----
        {
            const int crow = t >> 2;               // code within tile
            const int fb   = (t & 3) * 4;
            const float4* cr = (const float4*)(cb + (size_t)(c0 + crow) * 64);
#pragma unroll
            for (int j = 0; j < 4; ++j) {
                float4 v = cr[fb + j];
                const int d0 = (fb + j) * 4;
                cbT_raw[(d0 + 0) * 68 + crow] = v.x;
                cbT_raw[(d0 + 1) * 68 + crow] = v.y;
                cbT_raw[(d0 + 2) * 68 + crow] = v.z;
                cbT_raw[(d0 + 3) * 68 + crow] = v.w;
            }
        }
        __syncthreads();

        // ---- 4x4 micro-tile over 64 dims (ascending-dim fma chain == R1) ----
        float s[4][4];
#pragma unroll
        for (int i = 0; i < 4; ++i)
#pragma unroll
            for (int j = 0; j < 4; ++j) s[i][j] = 0.f;

#pragma unroll 4
        for (int kk = 0; kk < 16; ++kk) {
            float4 xf[4], cf[4];
#pragma unroll
            for (int i = 0; i < 4; ++i)
                xf[i] = *(const float4*)&x_lds[(4 * r + i) * 68 + kk * 4];
#pragma unroll
            for (int d = 0; d < 4; ++d)
                cf[d] = *(const float4*)&cbT_raw[(kk * 4 + d) * 68 + 4 * c];
#pragma unroll
            for (int d = 0; d < 4; ++d)
#pragma unroll
                for (int i = 0; i < 4; ++i) {
                    const float xv = f4c(xf[i], d);
#pragma unroll
                    for (int j = 0; j < 4; ++j)
                        s[i][j] = fmaf(xv, f4c(cf[d], j), s[i][j]);
                }
        }

        // ---- scores + running keyed argmin ----
#pragma unroll
        for (int j = 0; j < 4; ++j) {
            const int k = c0 + 4 * c + j;
            const float cn = cnorm[k];
#pragma unroll
            for (int i = 0; i < 4; ++i) {
                const float d = fmaf(-2.f, s[i][j], cn);
                const unsigned long long key =
                    ((unsigned long long)order_key(d) << 32) | (unsigned int)k;
                best[i] = key < best[i] ? key : best[i];
            }
        }
    }

    // ---- in-block argmin reduce (alias cbT as u64 red[64][17]) ----
    __syncthreads();
    unsigned long long* red = (unsigned long long*)cbT_raw;
#pragma unroll
    for (int i = 0; i < 4; ++i) red[(4 * r + i) * 17 + c] = best[i];
    __syncthreads();

    if (t < 64) {
        unsigned long long b = red[t * 17 + 0];
#pragma unroll
        for (int cc = 1; cc < 16; ++cc) {
            unsigned long long v = red[t * 17 + cc];
            b = v < b ? v : b;
        }
        const int idx = (int)(unsigned int)b;
        win[t] = idx;
        atomicAdd(&ws[1024 + idx], 1.0f);   // integer-valued: exact, order-indep
    }
    __syncthreads();

    // ---- fused epilogue: z_q_bar + commit-loss partial ----
    {
        const int tokr = t >> 2;
        const int fb   = (t & 3) * 4;
        const int idx  = win[tokr];
        const float4* cq = (const float4*)cb + (size_t)idx * 16;
        float4* o4 = (float4*)out + (size_t)(tok0 + tokr) * 16;
        float ss = 0.f;
#pragma unroll
        for (int j = 0; j < 4; ++j) {
            float4 xv = *(const float4*)&x_lds[tokr * 68 + (fb + j) * 4];
            float4 qv = cq[fb + j];
            float4 ov; float dx;
            dx = qv.x - xv.x; ov.x = xv.x + dx; ss = fmaf(dx, dx, ss);
            dx = qv.y - xv.y; ov.y = xv.y + dx; ss = fmaf(dx, dx, ss);
            dx = qv.z - xv.z; ov.z = xv.z + dx; ss = fmaf(dx, dx, ss);
            dx = qv.w - xv.w; ov.w = xv.w + dx; ss = fmaf(dx, dx, ss);
            o4[fb + j] = ov;
        }
        ss += __shfl_down(ss, 2, 64);   // quad lanes share a token
        ss += __shfl_down(ss, 1, 64);
        if ((t & 3) == 0) lsum[tokr] = ss * (1.f / 64.f);
    }
    __syncthreads();
    if (t < 64) {
        float v = lsum[t];
#pragma unroll
        for (int off = 32; off > 0; off >>= 1) v += __shfl_down(v, off, 64);
        if (t == 0) ws[2048 + blk] = v;
    }
}

__global__ void final_kernel(const float* __restrict__ ws, float* __restrict__ out) {
    __shared__ float red[1024];
    const int t = threadIdx.x;
    const float c = ws[1024 + t];

    red[t] = c; __syncthreads();
    for (int s = 512; s > 0; s >>= 1) { if (t < s) red[t] += red[t + s]; __syncthreads(); }
    const float total = fmaxf(red[0], 1e-6f);
    __syncthreads();

    const float p = c / total;
    red[t] = p * logf(p + 1e-7f); __syncthreads();
    for (int s = 512; s > 0; s >>= 1) { if (t < s) red[t] += red[t + s]; __syncthreads(); }
    const float ent = red[0];
    __syncthreads();

    red[t] = (c >= 1.f) ? 1.f : 0.f; __syncthreads();
    for (int s = 512; s > 0; s >>= 1) { if (t < s) red[t] += red[t + s]; __syncthreads(); }
    const float used = red[0];
    __syncthreads();

    red[t] = ws[2048 + t];   // 1024 block loss partials
    __syncthreads();
    for (int s = 512; s > 0; s >>= 1) { if (t < s) red[t] += red[t + s]; __syncthreads(); }

    if (t == 0) {
        out[OUT_SCALARS + 0] = red[0] * (1.f / (float)NTOK);
        out[OUT_SCALARS + 1] = expf(-ent);
        out[OUT_SCALARS + 2] = used * (1.f / (float)KCODE);
    }
}

extern "C" void kernel_launch(void* const* d_in, const int* in_sizes, int n_in,
                              void* d_out, int out_size, void* d_ws, size_t ws_size,
                              hipStream_t stream) {
    const float* z  = (const float*)d_in[0];
    const float* cb = (const float*)d_in[1];
    float* out = (float*)d_out;
    float* ws  = (float*)d_ws;   // 3072 floats = 12.3 KB

    prep_kernel <<<4, 256, 0, stream>>>(cb, ws);
    quant_kernel<<<NBLK, 256, 0, stream>>>(z, cb, out, ws);
    final_kernel<<<1, 1024, 0, stream>>>(ws, out);
}

// Round 5
// 137.478 us; speedup vs baseline: 3.3652x; 1.1547x over previous
//
#include <hip/hip_runtime.h>

// QuantizeEMAReset forward (eval): VQ quantize + commit loss + perplexity/usage.
// z: [16,4096,64] fp32 -> N=65536 tokens, C=64. codebook: [1024,64] fp32.
// out: [z_q_bar (4194304 f32), commit_loss, ppl, usage] flat.
//
// R5: fp16-split MFMA distance GEMM (dot = hihi + 2^-12*(hi*lo4096 + lo4096*hi),
// 6x mfma_f32_16x16x32_f16 per 16x16 tile). Per-lane top-2 + margin flag;
// flagged tokens exactly rescored in fp32 (R1 chain) by rescue kernel.
//
// ws float-index map:
//   [0,1024)     cnorm
//   [1024,2048)  counts
//   [2048,3072)  loss partials (per block)
//   3072         nflag (int)
//   [3073,7169)  flag list (int: tok | idx<<16)
//   [8192,40960) cbh halves (65536)
//   [40960,73728) cbl halves (65536)   total 288 KB

typedef _Float16 half8 __attribute__((ext_vector_type(8)));
typedef float f32x4 __attribute__((ext_vector_type(4)));

#define NTOK 65536
#define KCODE 1024
#define OUT_SCALARS 4194304
#define MARGIN 1e-3f
#define FLAG_CAP 4096

#define WS_CNORM 0
#define WS_CNT   1024
#define WS_LOSS  2048
#define WS_NFLAG 3072
#define WS_FLAGS 3073
#define WS_CBH   8192
#define WS_CBL   40960

static __device__ __forceinline__ unsigned int order_key(float f) {
    unsigned int u = __float_as_uint(f);
    unsigned int mask = (u >> 31) ? 0xFFFFFFFFu : 0x80000000u;
    return u ^ mask;   // monotone: a<b (float) <=> key(a)<key(b) (uint)
}

__global__ void prep_kernel(const float* __restrict__ cb, float* __restrict__ ws) {
    const int k = blockIdx.x * 256 + threadIdx.x;   // 0..1023
    const float4* cb4 = (const float4*)cb;
    float s = 0.f;
#pragma unroll
    for (int j = 0; j < 16; ++j) {
        float4 v = cb4[k * 16 + j];
        s = fmaf(v.x, v.x, s);
        s = fmaf(v.y, v.y, s);
        s = fmaf(v.z, v.z, s);
        s = fmaf(v.w, v.w, s);
    }
    ws[k] = s;             // cnorm: exact R1 chain
    ws[WS_CNT + k] = 0.f;  // zero histogram
    if (k == 0) *(int*)(ws + WS_NFLAG) = 0;

    _Float16* cbh = (_Float16*)(ws + WS_CBH);
    _Float16* cbl = (_Float16*)(ws + WS_CBL);
#pragma unroll
    for (int j8 = 0; j8 < 8; ++j8) {
        float4 a = cb4[k * 16 + 2 * j8], b = cb4[k * 16 + 2 * j8 + 1];
        float xf[8] = {a.x, a.y, a.z, a.w, b.x, b.y, b.z, b.w};
        half8 h, lo;
#pragma unroll
        for (int i = 0; i < 8; ++i) {
            _Float16 hi = (_Float16)xf[i];
            h[i] = hi;
            lo[i] = (_Float16)((xf[i] - (float)hi) * 4096.f);  // scaled: avoids f16 denorm flush
        }
        *(half8*)(cbh + k * 64 + j8 * 8) = h;
        *(half8*)(cbl + k * 64 + j8 * 8) = lo;
    }
}

__launch_bounds__(256, 4)
__global__ void quant_kernel(const float* __restrict__ z,
                             const float* __restrict__ cb,
                             float* __restrict__ out,
                             float* __restrict__ ws) {
    const int t = threadIdx.x, blk = blockIdx.x;
    const int w = t >> 6, l = t & 63;
    const int cl = l & 15, g = l >> 4;        // MFMA col-lane, k-group
    const int tokL = w * 16 + cl;             // local token (this lane's B column)
    const int tokG = blk * 64 + tokL;

    __shared__ __align__(16) float x_lds[64 * 68];          // fp32 x, stride 68
    __shared__ __align__(16) _Float16 cbLDS[2][2][16 * 72]; // [dbuf][hi/lo][code*72+dim]
    __shared__ int win[64];
    __shared__ float lsum[64];

    // ---- B fragments (persistent) + x_lds staging; covers each (tok,dim) once ----
    half8 zh[2], zl[2];
    {
        const float4* z4 = (const float4*)(z + (size_t)tokG * 64);
#pragma unroll
        for (int q = 0; q < 2; ++q) {
            float4 a = z4[2 * g + 8 * q], b = z4[2 * g + 8 * q + 1];
            *(float4*)&x_lds[tokL * 68 + g * 8 + 32 * q] = a;
            *(float4*)&x_lds[tokL * 68 + g * 8 + 32 * q + 4] = b;
            float xf[8] = {a.x, a.y, a.z, a.w, b.x, b.y, b.z, b.w};
#pragma unroll
            for (int i = 0; i < 8; ++i) {
                _Float16 h = (_Float16)xf[i];
                zh[q][i] = h;
                zl[q][i] = (_Float16)((xf[i] - (float)h) * 4096.f);
            }
        }
    }

    const _Float16* cbh = (const _Float16*)(ws + WS_CBH);
    const _Float16* cbl = (const _Float16*)(ws + WS_CBL);

    // staging role: threads 0-127 copy hi, 128-255 copy lo; 16B per thread per tile
    const int sc = (t & 127) >> 3, sh = (t & 7) * 8;
    const _Float16* ssrc = (t < 128 ? cbh : cbl);
    const int sbuf = (t >= 128);

    *(half8*)&cbLDS[0][sbuf][sc * 72 + sh] = *(const half8*)(ssrc + (size_t)sc * 64 + sh);
    __syncthreads();

    float d1 = 3.4e38f, d2 = 3.4e38f;
    int idx1 = 0;

    for (int tile = 0; tile < 64; ++tile) {
        const int c0 = tile * 16;
        const int cur = tile & 1;
        if (tile < 63) {   // stage next tile into other buffer
            *(half8*)&cbLDS[cur ^ 1][sbuf][sc * 72 + sh] =
                *(const half8*)(ssrc + (size_t)(c0 + 16 + sc) * 64 + sh);
        }
        const _Float16* lh = &cbLDS[cur][0][cl * 72 + g * 8];
        const _Float16* ll = &cbLDS[cur][1][cl * 72 + g * 8];
        half8 ah0 = *(const half8*)lh;
        half8 ah1 = *(const half8*)(lh + 32);
        half8 al0 = *(const half8*)ll;
        half8 al1 = *(const half8*)(ll + 32);

        f32x4 a1 = {0.f, 0.f, 0.f, 0.f}, a2 = {0.f, 0.f, 0.f, 0.f};
        a1 = __builtin_amdgcn_mfma_f32_16x16x32_f16(ah0, zh[0], a1, 0, 0, 0);
        a1 = __builtin_amdgcn_mfma_f32_16x16x32_f16(ah1, zh[1], a1, 0, 0, 0);
        a2 = __builtin_amdgcn_mfma_f32_16x16x32_f16(ah0, zl[0], a2, 0, 0, 0);
        a2 = __builtin_amdgcn_mfma_f32_16x16x32_f16(ah1, zl[1], a2, 0, 0, 0);
        a2 = __builtin_amdgcn_mfma_f32_16x16x32_f16(al0, zh[0], a2, 0, 0, 0);
        a2 = __builtin_amdgcn_mfma_f32_16x16x32_f16(al1, zh[1], a2, 0, 0, 0);

        const float4 cnv = *(const float4*)(ws + c0 + 4 * g);
        const float cna[4] = {cnv.x, cnv.y, cnv.z, cnv.w};
#pragma unroll
        for (int r = 0; r < 4; ++r) {
            // dot = hihi + 2^-12 * cross;  d = cnorm - 2*dot
            float dot = fmaf(a2[r], 2.44140625e-4f, a1[r]);
            float d = fmaf(-2.f, dot, cna[r]);
            const int kidx = c0 + 4 * g + r;
            bool lt = d < d1;                 // strict <, ascending kidx: first-min
            d2 = fminf(d2, fmaxf(d, d1));
            idx1 = lt ? kidx : idx1;
            d1 = fminf(d1, d);
        }
        __syncthreads();
    }

    // ---- merge 4 lanes per token (lanes cl, cl+16, cl+32, cl+48) ----
    unsigned long long key = ((unsigned long long)order_key(d1) << 32) | (unsigned)idx1;
#pragma unroll
    for (int off = 16; off <= 32; off <<= 1) {
        unsigned long long ok = __shfl_xor(key, off, 64);
        float od1 = __shfl_xor(d1, off, 64);
        float od2 = __shfl_xor(d2, off, 64);
        d2 = fminf(fminf(d2, od2), fmaxf(d1, od1));  // 2nd-min of union
        d1 = fminf(d1, od1);
        key = ok < key ? ok : key;
    }
    if (l < 16) {
        const int idx = (int)(unsigned)(key & 0xFFFFFFFFull);
        win[tokL] = idx;
        atomicAdd(&ws[WS_CNT + idx], 1.f);   // integer-valued: exact, order-indep
        if (d2 - d1 < MARGIN) {              // near-tie: flag for exact rescore
            int slot = atomicAdd((int*)(ws + WS_NFLAG), 1);
            if (slot < FLAG_CAP)
                ((int*)(ws + WS_FLAGS))[slot] = tokG | (idx << 16);
        }
    }
    __syncthreads();

    // ---- fused epilogue: z_q_bar + commit-loss partial ----
    {
        const int tokr = t >> 2, fb = (t & 3) * 4;
        const int idx = win[tokr];
        const float4* cq = (const float4*)cb + (size_t)idx * 16;
        float4* o4 = (float4*)out + (size_t)(blk * 64 + tokr) * 16;
        float ss = 0.f;
#pragma unroll
        for (int j = 0; j < 4; ++j) {
            float4 xv = *(const float4*)&x_lds[tokr * 68 + (fb + j) * 4];
            float4 qv = cq[fb + j];
            float4 ov; float dx;
            dx = qv.x - xv.x; ov.x = xv.x + dx; ss = fmaf(dx, dx, ss);
            dx = qv.y - xv.y; ov.y = xv.y + dx; ss = fmaf(dx, dx, ss);
            dx = qv.z - xv.z; ov.z = xv.z + dx; ss = fmaf(dx, dx, ss);
            dx = qv.w - xv.w; ov.w = xv.w + dx; ss = fmaf(dx, dx, ss);
            o4[fb + j] = ov;
        }
        ss += __shfl_down(ss, 2, 64);
        ss += __shfl_down(ss, 1, 64);
        if ((t & 3) == 0) lsum[tokr] = ss * (1.f / 64.f);
    }
    __syncthreads();
    if (t < 64) {
        float v = lsum[t];
#pragma unroll
        for (int off = 32; off > 0; off >>= 1) v += __shfl_down(v, off, 64);
        if (t == 0) ws[WS_LOSS + blk] = v;
    }
}

// Exact fp32 rescore (R1 chain) for flagged near-tie tokens.
__global__ void rescue_kernel(const float* __restrict__ z,
                              const float* __restrict__ cb,
                              float* __restrict__ out,
                              float* __restrict__ ws) {
    const int t = threadIdx.x;
    int nf = *(const int*)(ws + WS_NFLAG);
    if (nf > FLAG_CAP) nf = FLAG_CAP;
    __shared__ float xs[64];
    __shared__ unsigned long long rk[256];
    const float4* cb4 = (const float4*)cb;

    for (int i = blockIdx.x; i < nf; i += 256) {
        const int e = ((const int*)(ws + WS_FLAGS))[i];
        const int tok = e & 0xFFFF, oldidx = e >> 16;
        __syncthreads();
        if (t < 16) *(float4*)&xs[t * 4] = ((const float4*)(z + (size_t)tok * 64))[t];
        __syncthreads();

        unsigned long long best = ~0ull;
#pragma unroll
        for (int kk = 0; kk < 4; ++kk) {
            const int k = t * 4 + kk;
            float s = 0.f;
#pragma unroll
            for (int j = 0; j < 16; ++j) {
                float4 c = cb4[(size_t)k * 16 + j];
                float4 xv = *(const float4*)&xs[j * 4];
                s = fmaf(xv.x, c.x, s);
                s = fmaf(xv.y, c.y, s);
                s = fmaf(xv.z, c.z, s);
                s = fmaf(xv.w, c.w, s);
            }
            float d = fmaf(-2.f, s, ws[k]);   // exact R1 distance
            unsigned long long kkey = ((unsigned long long)order_key(d) << 32) | (unsigned)k;
            best = kkey < best ? kkey : best;
        }
        rk[t] = best; __syncthreads();
        for (int sft = 128; sft > 0; sft >>= 1) {
            if (t < sft) { unsigned long long o = rk[t + sft]; if (o < rk[t]) rk[t] = o; }
            __syncthreads();
        }
        if (t == 0) {
            const int ni = (int)(unsigned)(rk[0] & 0xFFFFFFFFull);
            if (ni != oldidx) {
                atomicAdd(&ws[WS_CNT + oldidx], -1.f);
                atomicAdd(&ws[WS_CNT + ni], 1.f);
                const float4* co = cb4 + (size_t)oldidx * 16;
                const float4* cn = cb4 + (size_t)ni * 16;
                float4* o4 = (float4*)out + (size_t)tok * 16;
                float sg_o[4], sg_n[4];
#pragma unroll
                for (int gq = 0; gq < 4; ++gq) {
                    float so = 0.f, sn = 0.f;
#pragma unroll
                    for (int j = 0; j < 4; ++j) {
                        float4 xv = *(const float4*)&xs[(gq * 4 + j) * 4];
                        float4 qo = co[gq * 4 + j], qn = cn[gq * 4 + j];
                        float dx;
                        dx = qo.x - xv.x; so = fmaf(dx, dx, so);
                        dx = qo.y - xv.y; so = fmaf(dx, dx, so);
                        dx = qo.z - xv.z; so = fmaf(dx, dx, so);
                        dx = qo.w - xv.w; so = fmaf(dx, dx, so);
                        float4 ov;
                        dx = qn.x - xv.x; ov.x = xv.x + dx; sn = fmaf(dx, dx, sn);
                        dx = qn.y - xv.y; ov.y = xv.y + dx; sn = fmaf(dx, dx, sn);
                        dx = qn.z - xv.z; ov.z = xv.z + dx; sn = fmaf(dx, dx, sn);
                        dx = qn.w - xv.w; ov.w = xv.w + dx; sn = fmaf(dx, dx, sn);
                        o4[gq * 4 + j] = ov;
                    }
                    sg_o[gq] = so; sg_n[gq] = sn;
                }
                float sso = (sg_o[0] + sg_o[2]) + (sg_o[1] + sg_o[3]);  // match quant shfl tree
                float ssn = (sg_n[0] + sg_n[2]) + (sg_n[1] + sg_n[3]);
                atomicAdd(&ws[WS_LOSS + (tok >> 6)], (ssn - sso) * (1.f / 64.f));
            }
        }
    }
}

__global__ void final_kernel(const float* __restrict__ ws, float* __restrict__ out) {
    __shared__ float red[1024];
    const int t = threadIdx.x;
    const float c = ws[WS_CNT + t];

    red[t] = c; __syncthreads();
    for (int s = 512; s > 0; s >>= 1) { if (t < s) red[t] += red[t + s]; __syncthreads(); }
    const float total = fmaxf(red[0], 1e-6f);
    __syncthreads();

    const float p = c / total;
    red[t] = p * logf(p + 1e-7f); __syncthreads();
    for (int s = 512; s > 0; s >>= 1) { if (t < s) red[t] += red[t + s]; __syncthreads(); }
    const float ent = red[0];
    __syncthreads();

    red[t] = (c >= 1.f) ? 1.f : 0.f; __syncthreads();
    for (int s = 512; s > 0; s >>= 1) { if (t < s) red[t] += red[t + s]; __syncthreads(); }
    const float used = red[0];
    __syncthreads();

    red[t] = ws[WS_LOSS + t];   // 1024 block partials
    __syncthreads();
    for (int s = 512; s > 0; s >>= 1) { if (t < s) red[t] += red[t + s]; __syncthreads(); }

    if (t == 0) {
        out[OUT_SCALARS + 0] = red[0] * (1.f / (float)NTOK);
        out[OUT_SCALARS + 1] = expf(-ent);
        out[OUT_SCALARS + 2] = used * (1.f / (float)KCODE);
    }
}

extern "C" void kernel_launch(void* const* d_in, const int* in_sizes, int n_in,
                              void* d_out, int out_size, void* d_ws, size_t ws_size,
                              hipStream_t stream) {
    const float* z  = (const float*)d_in[0];
    const float* cb = (const float*)d_in[1];
    float* out = (float*)d_out;
    float* ws  = (float*)d_ws;   // 288 KB used

    prep_kernel  <<<4, 256, 0, stream>>>(cb, ws);
    quant_kernel <<<NTOK / 64, 256, 0, stream>>>(z, cb, out, ws);
    rescue_kernel<<<256, 256, 0, stream>>>(z, cb, out, ws);
    final_kernel <<<1, 1024, 0, stream>>>(ws, out);
}